// Round 1
// baseline (932.785 us; speedup 1.0000x reference)
//
#include <hip/hip_runtime.h>

// MultiHeadAttention: B=4, S=4096, D=256 (single head, fp32 in/out)
// Pipeline: cvt(fp32->bf16) -> QKV GEMM (bf16 MFMA, V stored transposed)
//           -> flash attention (swapped QK^T, online softmax)
//           -> out-proj GEMM (fp32 out)

#define LOG2E 1.44269504088896340736f

typedef __attribute__((ext_vector_type(8))) short short8;
typedef __attribute__((ext_vector_type(4))) short short4v;
typedef __attribute__((ext_vector_type(4))) float f32x4;
typedef __attribute__((ext_vector_type(4))) float float4v;

static constexpr int BB = 4, SS = 4096, DD = 256;

// ws element offsets (shorts)
static constexpr size_t OFF_W1  = 0;                      // 3D*D = 196608
static constexpr size_t OFF_W2  = 196608;                 // D*D  = 65536
static constexpr size_t OFF_Q   = 262144;                 // B*S*D = 4194304
static constexpr size_t OFF_K   = 4456448;
static constexpr size_t OFF_VT  = 8650752;                // [B][D][S]
static constexpr size_t OFF_XB  = 12845056;               // x bf16, reused as VAL after qkv
static constexpr size_t OFF_VAL = 12845056;               // alias of XB (xb dead after qkv gemm)

__device__ __forceinline__ short f2bf(float f) {
    union { float f; unsigned u; } v; v.f = f;
    unsigned u = v.u;
    u += 0x7fffu + ((u >> 16) & 1u);   // round-to-nearest-even
    return (short)(u >> 16);
}

// ---------------- fp32 -> bf16 convert (x, W_qkv, W_o) ----------------
__global__ __launch_bounds__(256) void cvt_all(
    const float* __restrict__ x, const float* __restrict__ w1,
    const float* __restrict__ w2, short* __restrict__ xb,
    short* __restrict__ w1b, short* __restrict__ w2b)
{
    const int n_x = (BB * SS * DD) / 4;   // 1048576
    const int n_1 = (3 * DD * DD) / 4;    // 49152
    const int n_2 = (DD * DD) / 4;        // 16384
    int i = blockIdx.x * 256 + threadIdx.x;
    if (i >= n_x + n_1 + n_2) return;
    const float* src; short* dst; int off;
    if (i < n_x)            { src = x;  dst = xb;  off = i; }
    else if (i < n_x + n_1) { src = w1; dst = w1b; off = i - n_x; }
    else                    { src = w2; dst = w2b; off = i - n_x - n_1; }
    float4v v = *(const float4v*)(src + 4 * (size_t)off);
    short4v o;
    o[0] = f2bf(v[0]); o[1] = f2bf(v[1]); o[2] = f2bf(v[2]); o[3] = f2bf(v[3]);
    *(short4v*)(dst + 4 * (size_t)off) = o;
}

// ---------------- QKV projection: [16384,256] x [768,256]^T ----------------
// writes Q (scaled by 1/16) [b][s][d], K [b][s][d], V^T [b][d][s], all bf16
__global__ __launch_bounds__(256) void qkv_gemm(
    const short* __restrict__ xb, const short* __restrict__ wb,
    const float* __restrict__ bias,
    short* __restrict__ Qw, short* __restrict__ Kw, short* __restrict__ Vt)
{
    const int lane = threadIdx.x & 63;
    const int w    = threadIdx.x >> 6;
    const int ln = lane & 15, lg = lane >> 4;
    const int mbase = blockIdx.x * 64 + w * 16;
    const int nbase = blockIdx.y * 64;

    f32x4 acc[4] = {};
    const short* arow = xb + (size_t)(mbase + ln) * DD + 8 * lg;
#pragma unroll
    for (int kk = 0; kk < 8; ++kk) {
        short8 af = *(const short8*)(arow + 32 * kk);
#pragma unroll
        for (int nt = 0; nt < 4; ++nt) {
            short8 bf = *(const short8*)(wb + (size_t)(nbase + 16 * nt + ln) * DD + 32 * kk + 8 * lg);
            acc[nt] = __builtin_amdgcn_mfma_f32_16x16x32_bf16(af, bf, acc[nt], 0, 0, 0);
        }
    }
#pragma unroll
    for (int nt = 0; nt < 4; ++nt) {
        const int e = nbase + 16 * nt + ln;
        const float bv = bias[e];
        const int srow0 = mbase + 4 * lg;          // + r
        const int b   = srow0 >> 12;
        const int si0 = srow0 & 4095;
        if (e < 256) {
#pragma unroll
            for (int r = 0; r < 4; ++r) {
                float v = (acc[nt][r] + bv) * 0.0625f;   // fold 1/sqrt(256)
                Qw[((size_t)b * SS + si0 + r) * DD + e] = f2bf(v);
            }
        } else if (e < 512) {
#pragma unroll
            for (int r = 0; r < 4; ++r)
                Kw[((size_t)b * SS + si0 + r) * DD + (e - 256)] = f2bf(acc[nt][r] + bv);
        } else {
            short4v st;
#pragma unroll
            for (int r = 0; r < 4; ++r) st[r] = f2bf(acc[nt][r] + bv);
            *(short4v*)(Vt + ((size_t)b * DD + (e - 512)) * SS + si0) = st;
        }
    }
}

// ---------------- flash attention ----------------
// per wave: 16 q-rows. swapped S^T = K * Q^T; C layout: lane holds q=ln col,
// keys 4*lg+r (+16*kt +64*kb). P^T feeds PV MFMA B-operand directly.
__global__ __launch_bounds__(256) void attn(
    const short* __restrict__ Qw, const short* __restrict__ Kw,
    const short* __restrict__ Vt, short* __restrict__ Val)
{
    const int lane = threadIdx.x & 63;
    const int w    = threadIdx.x >> 6;
    const int ln = lane & 15, lg = lane >> 4;
    const int b = blockIdx.x >> 6;
    const int qbase = (blockIdx.x & 63) * 64 + w * 16;

    const short* Qp = Qw + ((size_t)b * SS + qbase + ln) * DD + 8 * lg;
    short8 qf[8];
#pragma unroll
    for (int kk = 0; kk < 8; ++kk) qf[kk] = *(const short8*)(Qp + 32 * kk);

    f32x4 O[16] = {};
    float m_run = -1e30f, l_part = 0.f;

    const short* Kbase = Kw + ((size_t)b * SS + ln) * DD + 8 * lg;
    const short* Vbase = Vt + ((size_t)b * DD + ln) * SS + 4 * lg;

    for (int kb = 0; kb < SS / 64; ++kb) {
        f32x4 sacc[4];
#pragma unroll
        for (int kt = 0; kt < 4; ++kt) {
            f32x4 a = {};
            const short* kp = Kbase + (size_t)(kb * 64 + kt * 16) * DD;
#pragma unroll
            for (int kk = 0; kk < 8; ++kk) {
                short8 kf = *(const short8*)(kp + 32 * kk);
                a = __builtin_amdgcn_mfma_f32_16x16x32_bf16(kf, qf[kk], a, 0, 0, 0);
            }
            sacc[kt] = a;
        }
        // online softmax (per q-column = ln; spread across 4 lane-groups)
        float pm = -1e30f;
#pragma unroll
        for (int kt = 0; kt < 4; ++kt)
#pragma unroll
            for (int r = 0; r < 4; ++r) pm = fmaxf(pm, sacc[kt][r]);
        pm = fmaxf(pm, __shfl_xor(pm, 16));
        pm = fmaxf(pm, __shfl_xor(pm, 32));
        const float mnew = fmaxf(m_run, pm);
        const float corr = exp2f((m_run - mnew) * LOG2E);
        m_run = mnew;
        float psum = 0.f;
        short pe[16];
#pragma unroll
        for (int kt = 0; kt < 4; ++kt)
#pragma unroll
            for (int r = 0; r < 4; ++r) {
                float p = exp2f((sacc[kt][r] - mnew) * LOG2E);
                psum += p;
                pe[kt * 4 + r] = f2bf(p);
            }
        l_part = l_part * corr + psum;
#pragma unroll
        for (int nt = 0; nt < 16; ++nt) O[nt] *= corr;
        short8 pb0, pb1;
#pragma unroll
        for (int j = 0; j < 8; ++j) { pb0[j] = pe[j]; pb1[j] = pe[8 + j]; }
        // PV: O^T[d][q] += V^T[d][key] * P^T[key][q]
        const short* vp0 = Vbase + kb * 64;
#pragma unroll
        for (int nt = 0; nt < 16; ++nt) {
            const short* vp = vp0 + (size_t)nt * 16 * SS;
#pragma unroll
            for (int h = 0; h < 2; ++h) {
                short4v v0 = *(const short4v*)(vp + 32 * h);
                short4v v1 = *(const short4v*)(vp + 32 * h + 16);
                short8 vf = { v0[0], v0[1], v0[2], v0[3], v1[0], v1[1], v1[2], v1[3] };
                O[nt] = __builtin_amdgcn_mfma_f32_16x16x32_bf16(vf, h ? pb1 : pb0, O[nt], 0, 0, 0);
            }
        }
    }
    float lt = l_part + __shfl_xor(l_part, 16);
    lt += __shfl_xor(lt, 32);
    const float inv = 1.0f / lt;
    short* vo = Val + ((size_t)b * SS + qbase + ln) * DD + 4 * lg;
#pragma unroll
    for (int nt = 0; nt < 16; ++nt) {
        short4v st;
#pragma unroll
        for (int r = 0; r < 4; ++r) st[r] = f2bf(O[nt][r] * inv);
        *(short4v*)(vo + nt * 16) = st;
    }
}

// ---------------- out projection: [16384,256] x [256,256]^T -> fp32 ----------------
__global__ __launch_bounds__(256) void oproj_gemm(
    const short* __restrict__ vb, const short* __restrict__ wb,
    const float* __restrict__ bias, float* __restrict__ out)
{
    const int lane = threadIdx.x & 63;
    const int w    = threadIdx.x >> 6;
    const int ln = lane & 15, lg = lane >> 4;
    const int mbase = blockIdx.x * 64 + w * 16;
    const int nbase = blockIdx.y * 64;

    f32x4 acc[4] = {};
    const short* arow = vb + (size_t)(mbase + ln) * DD + 8 * lg;
#pragma unroll
    for (int kk = 0; kk < 8; ++kk) {
        short8 af = *(const short8*)(arow + 32 * kk);
#pragma unroll
        for (int nt = 0; nt < 4; ++nt) {
            short8 bf = *(const short8*)(wb + (size_t)(nbase + 16 * nt + ln) * DD + 32 * kk + 8 * lg);
            acc[nt] = __builtin_amdgcn_mfma_f32_16x16x32_bf16(af, bf, acc[nt], 0, 0, 0);
        }
    }
#pragma unroll
    for (int nt = 0; nt < 4; ++nt) {
        const int e = nbase + 16 * nt + ln;
        const float bv = bias[e];
#pragma unroll
        for (int r = 0; r < 4; ++r)
            out[(size_t)(mbase + 4 * lg + r) * DD + e] = acc[nt][r] + bv;
    }
}

extern "C" void kernel_launch(void* const* d_in, const int* in_sizes, int n_in,
                              void* d_out, int out_size, void* d_ws, size_t ws_size,
                              hipStream_t stream) {
    const float* x    = (const float*)d_in[0];
    const float* Wqkv = (const float*)d_in[1];
    const float* bqkv = (const float*)d_in[2];
    const float* Wo   = (const float*)d_in[3];
    const float* bo   = (const float*)d_in[4];
    float* out = (float*)d_out;
    short* ws  = (short*)d_ws;

    short* w1b = ws + OFF_W1;
    short* w2b = ws + OFF_W2;
    short* Qw  = ws + OFF_Q;
    short* Kw  = ws + OFF_K;
    short* Vt  = ws + OFF_VT;
    short* xb  = ws + OFF_XB;
    short* Val = ws + OFF_VAL;   // aliases xb (dead after qkv_gemm)

    cvt_all<<<4352, 256, 0, stream>>>(x, Wqkv, Wo, xb, w1b, w2b);
    qkv_gemm<<<dim3(256, 12), 256, 0, stream>>>(xb, w1b, bqkv, Qw, Kw, Vt);
    attn<<<256, 256, 0, stream>>>(Qw, Kw, Vt, Val);
    oproj_gemm<<<dim3(256, 4), 256, 0, stream>>>(Val, w2b, bo, out);
}

// Round 2
// 724.174 us; speedup vs baseline: 1.2881x; 1.2881x over previous
//
#include <hip/hip_runtime.h>

// MultiHeadAttention: B=4, S=4096, D=256 (single head, fp32 in/out)
// cvt(fp32->bf16) -> QKV GEMM (bf16 MFMA, V transposed) ->
// split-K flash attention (K staged in LDS w/ XOR swizzle, online softmax)
// -> combine -> out-proj GEMM (fp32 out)

#define LOG2E 1.44269504088896340736f

typedef __attribute__((ext_vector_type(8))) short short8;
typedef __attribute__((ext_vector_type(4))) short short4v;
typedef __attribute__((ext_vector_type(4))) float f32x4;
typedef __attribute__((ext_vector_type(4))) float float4v;
typedef __attribute__((ext_vector_type(2))) float float2v;

static constexpr int BB = 4, SS = 4096, DD = 256;
static constexpr int KSPLIT = 4;

// ws element offsets (shorts)
static constexpr size_t OFF_W1  = 0;                      // 3D*D
static constexpr size_t OFF_W2  = 196608;                 // D*D
static constexpr size_t OFF_Q   = 262144;                 // B*S*D
static constexpr size_t OFF_K   = 4456448;
static constexpr size_t OFF_VT  = 8650752;                // [B][D][S]
static constexpr size_t OFF_XB  = 12845056;               // x bf16; reused as VAL
static constexpr size_t OFF_VAL = 12845056;
static constexpr size_t OFF_OP  = 17039360;               // partial O bf16, KSPLIT*B*S*D
static constexpr size_t OFF_ML  = 17039360 + (size_t)KSPLIT * BB * SS * DD; // float2 region
static constexpr size_t WS_NEED_SPLIT = (OFF_ML + (size_t)BB * SS * KSPLIT * 2) * 2; // bytes

__device__ __forceinline__ short f2bf(float f) {
    union { float f; unsigned u; } v; v.f = f;
    unsigned u = v.u;
    u += 0x7fffu + ((u >> 16) & 1u);
    return (short)(u >> 16);
}
__device__ __forceinline__ float bf2f(short s) {
    union { unsigned u; float f; } v; v.u = ((unsigned)(unsigned short)s) << 16;
    return v.f;
}
__device__ __forceinline__ void gload_lds16(const void* g, void* l) {
    __builtin_amdgcn_global_load_lds(
        (const __attribute__((address_space(1))) unsigned int*)g,
        (__attribute__((address_space(3))) unsigned int*)l, 16, 0, 0);
}

// ---------------- fp32 -> bf16 convert ----------------
__global__ __launch_bounds__(256) void cvt_all(
    const float* __restrict__ x, const float* __restrict__ w1,
    const float* __restrict__ w2, short* __restrict__ xb,
    short* __restrict__ w1b, short* __restrict__ w2b)
{
    const int n_x = (BB * SS * DD) / 4;
    const int n_1 = (3 * DD * DD) / 4;
    const int n_2 = (DD * DD) / 4;
    int i = blockIdx.x * 256 + threadIdx.x;
    if (i >= n_x + n_1 + n_2) return;
    const float* src; short* dst; int off;
    if (i < n_x)            { src = x;  dst = xb;  off = i; }
    else if (i < n_x + n_1) { src = w1; dst = w1b; off = i - n_x; }
    else                    { src = w2; dst = w2b; off = i - n_x - n_1; }
    float4v v = *(const float4v*)(src + 4 * (size_t)off);
    short4v o;
    o[0] = f2bf(v[0]); o[1] = f2bf(v[1]); o[2] = f2bf(v[2]); o[3] = f2bf(v[3]);
    *(short4v*)(dst + 4 * (size_t)off) = o;
}

// ---------------- QKV projection ----------------
__global__ __launch_bounds__(256) void qkv_gemm(
    const short* __restrict__ xb, const short* __restrict__ wb,
    const float* __restrict__ bias,
    short* __restrict__ Qw, short* __restrict__ Kw, short* __restrict__ Vt)
{
    const int lane = threadIdx.x & 63;
    const int w    = threadIdx.x >> 6;
    const int ln = lane & 15, lg = lane >> 4;
    const int mbase = blockIdx.x * 64 + w * 16;
    const int nbase = blockIdx.y * 64;

    f32x4 acc[4] = {};
    const short* arow = xb + (size_t)(mbase + ln) * DD + 8 * lg;
#pragma unroll
    for (int kk = 0; kk < 8; ++kk) {
        short8 af = *(const short8*)(arow + 32 * kk);
#pragma unroll
        for (int nt = 0; nt < 4; ++nt) {
            short8 bf = *(const short8*)(wb + (size_t)(nbase + 16 * nt + ln) * DD + 32 * kk + 8 * lg);
            acc[nt] = __builtin_amdgcn_mfma_f32_16x16x32_bf16(af, bf, acc[nt], 0, 0, 0);
        }
    }
#pragma unroll
    for (int nt = 0; nt < 4; ++nt) {
        const int e = nbase + 16 * nt + ln;
        const float bv = bias[e];
        const int srow0 = mbase + 4 * lg;
        const int b   = srow0 >> 12;
        const int si0 = srow0 & 4095;
        if (e < 256) {
#pragma unroll
            for (int r = 0; r < 4; ++r) {
                float v = (acc[nt][r] + bv) * 0.0625f;
                Qw[((size_t)b * SS + si0 + r) * DD + e] = f2bf(v);
            }
        } else if (e < 512) {
#pragma unroll
            for (int r = 0; r < 4; ++r)
                Kw[((size_t)b * SS + si0 + r) * DD + (e - 256)] = f2bf(acc[nt][r] + bv);
        } else {
            short4v st;
#pragma unroll
            for (int r = 0; r < 4; ++r) st[r] = f2bf(acc[nt][r] + bv);
            *(short4v*)(Vt + ((size_t)b * DD + (e - 512)) * SS + si0) = st;
        }
    }
}

// ---------------- split-K flash attention ----------------
// grid (qtile=64, ks=KSP, b=4), 4 waves x 16 q-rows. K tile (64x256 bf16, 32KB)
// staged in LDS via global_load_lds, XOR-swizzled ((row&7)<<4 on bytes) via
// pre-swizzled global source. V read from global (L2).
template<int KSP>
__global__ __launch_bounds__(256, 4) void attn(
    const short* __restrict__ Qw, const short* __restrict__ Kw,
    const short* __restrict__ Vt, short* __restrict__ Opart,
    float* __restrict__ Ml, short* __restrict__ Val)
{
    constexpr int KCHUNK = SS / KSP;
    constexpr int NKB = KCHUNK / 64;
    __shared__ short Kt[64 * 256];   // 32KB

    const int lane = threadIdx.x & 63;
    const int w    = threadIdx.x >> 6;
    const int ln = lane & 15, lg = lane >> 4;
    const int b  = blockIdx.z;
    const int ks = blockIdx.y;
    const int qbase = blockIdx.x * 64 + w * 16;
    const int kbeg = ks * KCHUNK;

    const short* Qp = Qw + ((size_t)b * SS + qbase + ln) * DD + 8 * lg;
    short8 qf[8];
#pragma unroll
    for (int kk = 0; kk < 8; ++kk) qf[kk] = *(const short8*)(Qp + 32 * kk);

    f32x4 O[16] = {};
    float m_run = -1e30f, l_part = 0.f;

    const char* Kg = (const char*)(Kw + ((size_t)b * SS + kbeg) * DD);  // tile stream
    const short* Vbase = Vt + ((size_t)b * DD + ln) * SS + kbeg + 4 * lg;

    // prologue: stage tile 0 (each wave stages its 8KB quarter, linear dest,
    // swizzled source so LDS ends up XOR-swizzled)
#pragma unroll
    for (int i = 0; i < 8; ++i) {
        int o = w * 8192 + i * 1024 + lane * 16;
        int src = o ^ (((o >> 9) & 7) << 4);
        gload_lds16(Kg + src, (char*)Kt + (w * 8192 + i * 1024));
    }
    __syncthreads();

    for (int kb = 0; kb < NKB; ++kb) {
        // QK^T from LDS (swizzled reads)
        f32x4 sacc[4];
#pragma unroll
        for (int kt = 0; kt < 4; ++kt) {
            f32x4 a = {};
#pragma unroll
            for (int kk = 0; kk < 8; ++kk) {
                int idx = ((kt * 16 + ln) * 256 + kk * 32 + lg * 8) ^ ((ln & 7) << 3);
                short8 kf = *(const short8*)(Kt + idx);
                a = __builtin_amdgcn_mfma_f32_16x16x32_bf16(kf, qf[kk], a, 0, 0, 0);
            }
            sacc[kt] = a;
        }
        __syncthreads();   // all waves done reading K tile
        if (kb + 1 < NKB) {
            const char* Kgn = Kg + (size_t)(kb + 1) * 32768;
#pragma unroll
            for (int i = 0; i < 8; ++i) {
                int o = w * 8192 + i * 1024 + lane * 16;
                int src = o ^ (((o >> 9) & 7) << 4);
                gload_lds16(Kgn + src, (char*)Kt + (w * 8192 + i * 1024));
            }
        }
        // online softmax (overlaps the staging above)
        float pm = -1e30f;
#pragma unroll
        for (int kt = 0; kt < 4; ++kt)
#pragma unroll
            for (int r = 0; r < 4; ++r) pm = fmaxf(pm, sacc[kt][r]);
        pm = fmaxf(pm, __shfl_xor(pm, 16));
        pm = fmaxf(pm, __shfl_xor(pm, 32));
        const float mnew = fmaxf(m_run, pm);
        const float corr = exp2f((m_run - mnew) * LOG2E);
        m_run = mnew;
        float psum = 0.f;
        short pe[16];
#pragma unroll
        for (int kt = 0; kt < 4; ++kt)
#pragma unroll
            for (int r = 0; r < 4; ++r) {
                float p = exp2f((sacc[kt][r] - mnew) * LOG2E);
                psum += p;
                pe[kt * 4 + r] = f2bf(p);
            }
        l_part = l_part * corr + psum;
#pragma unroll
        for (int nt = 0; nt < 16; ++nt) O[nt] *= corr;
        short8 pb0, pb1;
#pragma unroll
        for (int j = 0; j < 8; ++j) { pb0[j] = pe[j]; pb1[j] = pe[8 + j]; }
        // PV from global V^T
        const short* vp0 = Vbase + kb * 64;
#pragma unroll
        for (int nt = 0; nt < 16; ++nt) {
            const short* vp = vp0 + (size_t)nt * 16 * SS;
#pragma unroll
            for (int h = 0; h < 2; ++h) {
                short4v v0 = *(const short4v*)(vp + 32 * h);
                short4v v1 = *(const short4v*)(vp + 32 * h + 16);
                short8 vf = { v0[0], v0[1], v0[2], v0[3], v1[0], v1[1], v1[2], v1[3] };
                O[nt] = __builtin_amdgcn_mfma_f32_16x16x32_bf16(vf, h ? pb1 : pb0, O[nt], 0, 0, 0);
            }
        }
        __syncthreads();   // staged tile (and V loads) complete
    }

    float lt = l_part + __shfl_xor(l_part, 16);
    lt += __shfl_xor(lt, 32);
    const float inv = 1.0f / lt;
    if constexpr (KSP == 1) {
        short* vo = Val + ((size_t)b * SS + qbase + ln) * DD + 4 * lg;
#pragma unroll
        for (int nt = 0; nt < 16; ++nt) {
            short4v st;
#pragma unroll
            for (int r = 0; r < 4; ++r) st[r] = f2bf(O[nt][r] * inv);
            *(short4v*)(vo + nt * 16) = st;
        }
    } else {
        short* vo = Opart + ((size_t)ks * (BB * SS) + (size_t)b * SS + qbase + ln) * DD + 4 * lg;
#pragma unroll
        for (int nt = 0; nt < 16; ++nt) {
            short4v st;
#pragma unroll
            for (int r = 0; r < 4; ++r) st[r] = f2bf(O[nt][r] * inv);
            *(short4v*)(vo + nt * 16) = st;
        }
        if (lg == 0) {
            float2v ml; ml[0] = m_run; ml[1] = lt;
            *(float2v*)(Ml + ((size_t)((size_t)b * SS + qbase + ln) * KSP + ks) * 2) = ml;
        }
    }
}

// ---------------- split combine ----------------
__global__ __launch_bounds__(256) void combine(
    const short* __restrict__ Opart, const float* __restrict__ Ml,
    short* __restrict__ Val)
{
    const int row = blockIdx.x;         // b*SS + s
    const int d = threadIdx.x;
    float m[KSPLIT], l[KSPLIT];
    float M = -1e30f;
#pragma unroll
    for (int i = 0; i < KSPLIT; ++i) {
        float2v v = *(const float2v*)(Ml + ((size_t)row * KSPLIT + i) * 2);
        m[i] = v[0]; l[i] = v[1];
        M = fmaxf(M, m[i]);
    }
    float wsum = 0.f, acc = 0.f;
#pragma unroll
    for (int i = 0; i < KSPLIT; ++i) {
        float wgt = l[i] * exp2f((m[i] - M) * LOG2E);
        wsum += wgt;
        acc += wgt * bf2f(Opart[(size_t)i * (BB * SS * DD) + (size_t)row * DD + d]);
    }
    Val[(size_t)row * DD + d] = f2bf(acc / wsum);
}

// ---------------- out projection -> fp32 ----------------
__global__ __launch_bounds__(256) void oproj_gemm(
    const short* __restrict__ vb, const short* __restrict__ wb,
    const float* __restrict__ bias, float* __restrict__ out)
{
    const int lane = threadIdx.x & 63;
    const int w    = threadIdx.x >> 6;
    const int ln = lane & 15, lg = lane >> 4;
    const int mbase = blockIdx.x * 64 + w * 16;
    const int nbase = blockIdx.y * 64;

    f32x4 acc[4] = {};
    const short* arow = vb + (size_t)(mbase + ln) * DD + 8 * lg;
#pragma unroll
    for (int kk = 0; kk < 8; ++kk) {
        short8 af = *(const short8*)(arow + 32 * kk);
#pragma unroll
        for (int nt = 0; nt < 4; ++nt) {
            short8 bf = *(const short8*)(wb + (size_t)(nbase + 16 * nt + ln) * DD + 32 * kk + 8 * lg);
            acc[nt] = __builtin_amdgcn_mfma_f32_16x16x32_bf16(af, bf, acc[nt], 0, 0, 0);
        }
    }
#pragma unroll
    for (int nt = 0; nt < 4; ++nt) {
        const int e = nbase + 16 * nt + ln;
        const float bv = bias[e];
#pragma unroll
        for (int r = 0; r < 4; ++r)
            out[(size_t)(mbase + 4 * lg + r) * DD + e] = acc[nt][r] + bv;
    }
}

extern "C" void kernel_launch(void* const* d_in, const int* in_sizes, int n_in,
                              void* d_out, int out_size, void* d_ws, size_t ws_size,
                              hipStream_t stream) {
    const float* x    = (const float*)d_in[0];
    const float* Wqkv = (const float*)d_in[1];
    const float* bqkv = (const float*)d_in[2];
    const float* Wo   = (const float*)d_in[3];
    const float* bo   = (const float*)d_in[4];
    float* out = (float*)d_out;
    short* ws  = (short*)d_ws;

    short* w1b = ws + OFF_W1;
    short* w2b = ws + OFF_W2;
    short* Qw  = ws + OFF_Q;
    short* Kw  = ws + OFF_K;
    short* Vt  = ws + OFF_VT;
    short* xb  = ws + OFF_XB;
    short* Val = ws + OFF_VAL;
    short* Opart = ws + OFF_OP;
    float* Ml  = (float*)(ws + OFF_ML);

    cvt_all<<<4352, 256, 0, stream>>>(x, Wqkv, Wo, xb, w1b, w2b);
    qkv_gemm<<<dim3(256, 12), 256, 0, stream>>>(xb, w1b, bqkv, Qw, Kw, Vt);
    if (ws_size >= WS_NEED_SPLIT) {
        attn<KSPLIT><<<dim3(64, KSPLIT, BB), 256, 0, stream>>>(Qw, Kw, Vt, Opart, Ml, nullptr);
        combine<<<BB * SS, 256, 0, stream>>>(Opart, Ml, Val);
    } else {
        attn<1><<<dim3(64, 1, BB), 256, 0, stream>>>(Qw, Kw, Vt, nullptr, nullptr, Val);
    }
    oproj_gemm<<<dim3(256, 4), 256, 0, stream>>>(Val, w2b, bo, out);
}

// Round 3
// 225.664 us; speedup vs baseline: 4.1335x; 3.2091x over previous
//
#include <hip/hip_runtime.h>

// MultiHeadAttention: B=4, S=4096, D=256 (single head, fp32 in/out)
// cvt -> QKV GEMM -> 8-wave 32x32 flash attention (K+V dbuf LDS, split-K)
// -> combine -> out-proj GEMM

#define LOG2E 1.44269504088896340736f

typedef __attribute__((ext_vector_type(8)))  short short8;
typedef __attribute__((ext_vector_type(4)))  short short4v;
typedef __attribute__((ext_vector_type(4)))  float f32x4;
typedef __attribute__((ext_vector_type(16))) float f32x16;
typedef __attribute__((ext_vector_type(4)))  float float4v;
typedef __attribute__((ext_vector_type(2)))  float float2v;

static constexpr int BB = 4, SS = 4096, DD = 256;
static constexpr int KSPLIT = 4;

// ws element offsets (shorts)
static constexpr size_t OFF_W1  = 0;
static constexpr size_t OFF_W2  = 196608;
static constexpr size_t OFF_Q   = 262144;
static constexpr size_t OFF_K   = 4456448;
static constexpr size_t OFF_VT  = 8650752;                // [B][D][S]
static constexpr size_t OFF_XB  = 12845056;               // x bf16; reused as VAL
static constexpr size_t OFF_VAL = 12845056;
static constexpr size_t OFF_OP  = 17039360;               // partial O bf16
static constexpr size_t OFF_ML  = 17039360 + (size_t)KSPLIT * BB * SS * DD;
static constexpr size_t WS_NEED_SPLIT = (OFF_ML + (size_t)BB * SS * KSPLIT * 2) * 2;

__device__ __forceinline__ short f2bf(float f) {
    union { float f; unsigned u; } v; v.f = f;
    unsigned u = v.u;
    u += 0x7fffu + ((u >> 16) & 1u);
    return (short)(u >> 16);
}
__device__ __forceinline__ float bf2f(short s) {
    union { unsigned u; float f; } v; v.u = ((unsigned)(unsigned short)s) << 16;
    return v.f;
}
__device__ __forceinline__ void gload_lds16(const void* g, void* l) {
    __builtin_amdgcn_global_load_lds(
        (const __attribute__((address_space(1))) unsigned int*)g,
        (__attribute__((address_space(3))) unsigned int*)l, 16, 0, 0);
}

// ---------------- fp32 -> bf16 convert ----------------
__global__ __launch_bounds__(256) void cvt_all(
    const float* __restrict__ x, const float* __restrict__ w1,
    const float* __restrict__ w2, short* __restrict__ xb,
    short* __restrict__ w1b, short* __restrict__ w2b)
{
    const int n_x = (BB * SS * DD) / 4;
    const int n_1 = (3 * DD * DD) / 4;
    const int n_2 = (DD * DD) / 4;
    int i = blockIdx.x * 256 + threadIdx.x;
    if (i >= n_x + n_1 + n_2) return;
    const float* src; short* dst; int off;
    if (i < n_x)            { src = x;  dst = xb;  off = i; }
    else if (i < n_x + n_1) { src = w1; dst = w1b; off = i - n_x; }
    else                    { src = w2; dst = w2b; off = i - n_x - n_1; }
    float4v v = *(const float4v*)(src + 4 * (size_t)off);
    short4v o;
    o[0] = f2bf(v[0]); o[1] = f2bf(v[1]); o[2] = f2bf(v[2]); o[3] = f2bf(v[3]);
    *(short4v*)(dst + 4 * (size_t)off) = o;
}

// ---------------- QKV projection ----------------
__global__ __launch_bounds__(256) void qkv_gemm(
    const short* __restrict__ xb, const short* __restrict__ wb,
    const float* __restrict__ bias,
    short* __restrict__ Qw, short* __restrict__ Kw, short* __restrict__ Vt)
{
    const int lane = threadIdx.x & 63;
    const int w    = threadIdx.x >> 6;
    const int ln = lane & 15, lg = lane >> 4;
    const int mbase = blockIdx.x * 64 + w * 16;
    const int nbase = blockIdx.y * 64;

    f32x4 acc[4] = {};
    const short* arow = xb + (size_t)(mbase + ln) * DD + 8 * lg;
#pragma unroll
    for (int kk = 0; kk < 8; ++kk) {
        short8 af = *(const short8*)(arow + 32 * kk);
#pragma unroll
        for (int nt = 0; nt < 4; ++nt) {
            short8 bf = *(const short8*)(wb + (size_t)(nbase + 16 * nt + ln) * DD + 32 * kk + 8 * lg);
            acc[nt] = __builtin_amdgcn_mfma_f32_16x16x32_bf16(af, bf, acc[nt], 0, 0, 0);
        }
    }
#pragma unroll
    for (int nt = 0; nt < 4; ++nt) {
        const int e = nbase + 16 * nt + ln;
        const float bv = bias[e];
        const int srow0 = mbase + 4 * lg;
        const int b   = srow0 >> 12;
        const int si0 = srow0 & 4095;
        if (e < 256) {
#pragma unroll
            for (int r = 0; r < 4; ++r) {
                float v = (acc[nt][r] + bv) * 0.0625f;
                Qw[((size_t)b * SS + si0 + r) * DD + e] = f2bf(v);
            }
        } else if (e < 512) {
#pragma unroll
            for (int r = 0; r < 4; ++r)
                Kw[((size_t)b * SS + si0 + r) * DD + (e - 256)] = f2bf(acc[nt][r] + bv);
        } else {
            short4v st;
#pragma unroll
            for (int r = 0; r < 4; ++r) st[r] = f2bf(acc[nt][r] + bv);
            *(short4v*)(Vt + ((size_t)b * DD + (e - 512)) * SS + si0) = st;
        }
    }
}

// ---------------- 8-wave 32x32 split-K flash attention ----------------
// Block: 512 thr = 8 waves, each wave 32 q-rows (256/block). KVBLK=64.
// K tile [64][256] (32KB) + V^T tile [256][64] (32KB), both XOR-swizzled
// ((row&7)<<4 bytes), double-buffered in 128KB dynamic LDS.
// Swapped QK^T: S^T = K*Q^T (32x32x16). C layout: col=lane&31 (q),
// row key = (reg&3)+8*(reg>>2)+4*hi. PV uses permuted-k so P feeds B directly.
template<int KSP>
__global__ __launch_bounds__(512, 2) void attn(
    const short* __restrict__ Qw, const short* __restrict__ Kw,
    const short* __restrict__ Vt, short* __restrict__ Opart,
    float* __restrict__ Ml, short* __restrict__ Val)
{
    constexpr int KCHUNK = SS / KSP;
    constexpr int NKB = KCHUNK / 64;
    extern __shared__ __align__(128) char smem[];   // [K0|K1|V0|V1] 32KB each

    const int id = blockIdx.x;
    const int combo = id % (KSP * BB);
    const int qb    = id / (KSP * BB);
    const int ks = combo % KSP;
    const int b  = combo / KSP;
    const int t = threadIdx.x;
    const int lane = t & 63, w = t >> 6;
    const int lr = lane & 31, hi = lane >> 5;
    const int q0 = qb * 256 + w * 32;
    const int kbeg = ks * KCHUNK;
    const int swz = (lr & 7) << 4;

    // Q fragments: B-operand, lane holds Q[q0+lr][16c+8hi .. +7]
    const short* Qp = Qw + ((size_t)b * SS + q0 + lr) * DD + 8 * hi;
    short8 qf[16];
#pragma unroll
    for (int c = 0; c < 16; ++c) qf[c] = *(const short8*)(Qp + 16 * c);

    f32x16 o_acc[8] = {};
    float m_run = -1e30f, l_part = 0.f;

    const char* Kg0 = (const char*)(Kw + ((size_t)b * SS + kbeg) * DD);
    const char* Vg0 = (const char*)(Vt + (size_t)b * DD * SS + kbeg);

    auto stage = [&](int buf, int kb) {
        char* kd = smem + buf * 32768;
        char* vd = smem + 65536 + buf * 32768;
        const char* kg = Kg0 + (size_t)kb * 32768;         // 64 rows * 512B
        const char* vg = Vg0 + (size_t)kb * 128;           // 64 keys * 2B in each d-row
#pragma unroll
        for (int i = 0; i < 4; ++i) {
            int o = i * 8192 + t * 16;
            int key = o >> 9, db = o & 511;
            gload_lds16(kg + ((size_t)key << 9) + (db ^ ((key & 7) << 4)), kd + o);
            int d = o >> 7, kby = o & 127;
            gload_lds16(vg + (size_t)d * 8192 + (kby ^ ((d & 7) << 4)), vd + o);
        }
    };

    stage(0, 0);
    __syncthreads();
    int cur = 0;

    for (int kb = 0; kb < NKB; ++kb) {
        if (kb + 1 < NKB) stage(cur ^ 1, kb + 1);

        const char* Kb = smem + cur * 32768;
        const char* Vb = smem + 65536 + cur * 32768;

        // QK^T: S^T[key][q], two 32-key tiles
        f32x16 sacc[2] = {};
#pragma unroll
        for (int c = 0; c < 16; ++c) {
#pragma unroll
            for (int kt = 0; kt < 2; ++kt) {
                short8 kf = *(const short8*)(Kb + (kt * 32 + lr) * 512 + ((c * 32 + hi * 16) ^ swz));
                sacc[kt] = __builtin_amdgcn_mfma_f32_32x32x16_bf16(kf, qf[c], sacc[kt], 0, 0, 0);
            }
        }

        // online softmax (each q col held by lanes l, l+32)
        float pm = -1e30f;
#pragma unroll
        for (int kt = 0; kt < 2; ++kt)
#pragma unroll
            for (int r = 0; r < 16; ++r) pm = fmaxf(pm, sacc[kt][r]);
        pm = fmaxf(pm, __shfl_xor(pm, 32));
        const float mnew = fmaxf(m_run, pm);
        const float corr = exp2f((m_run - mnew) * LOG2E);
        m_run = mnew;
        float psum = 0.f;
#pragma unroll
        for (int kt = 0; kt < 2; ++kt)
#pragma unroll
            for (int r = 0; r < 16; ++r) {
                float p = exp2f((sacc[kt][r] - mnew) * LOG2E);
                psum += p;
                sacc[kt][r] = p;
            }
        l_part = l_part * corr + psum;
#pragma unroll
        for (int dt = 0; dt < 8; ++dt)
#pragma unroll
            for (int r = 0; r < 16; ++r) o_acc[dt][r] *= corr;

        // PV: O^T[d][q] += V^T[d][key] * P^T[key][q], permuted k within 16
#pragma unroll
        for (int s = 0; s < 4; ++s) {
            short8 pb;
#pragma unroll
            for (int j = 0; j < 8; ++j)
                pb[j] = f2bf(sacc[s >> 1][(j & 3) + 4 * (j >> 2) + 8 * (s & 1)]);
            const int c1 = (32 * s + 8 * hi) ^ swz;
            const int c2 = (32 * s + 8 * hi + 16) ^ swz;
#pragma unroll
            for (int dt = 0; dt < 8; ++dt) {
                const char* vrow = Vb + (dt * 32 + lr) * 128;
                short4v v0 = *(const short4v*)(vrow + c1);
                short4v v1 = *(const short4v*)(vrow + c2);
                short8 vf = { v0[0], v0[1], v0[2], v0[3], v1[0], v1[1], v1[2], v1[3] };
                o_acc[dt] = __builtin_amdgcn_mfma_f32_32x32x16_bf16(vf, pb, o_acc[dt], 0, 0, 0);
            }
        }
        __syncthreads();     // staged tile landed; everyone done reading cur
        cur ^= 1;
    }

    float lt = l_part + __shfl_xor(l_part, 32);
    const float inv = 1.0f / lt;
    const size_t row = (size_t)b * SS + q0 + lr;
    short* vo = (KSP == 1 ? Val : Opart + (size_t)ks * (BB * SS) * DD)
                + row * DD;
#pragma unroll
    for (int dt = 0; dt < 8; ++dt)
#pragma unroll
        for (int g = 0; g < 4; ++g) {
            short4v st;
#pragma unroll
            for (int i = 0; i < 4; ++i) st[i] = f2bf(o_acc[dt][4 * g + i] * inv);
            *(short4v*)(vo + dt * 32 + 8 * g + 4 * hi) = st;
        }
    if (KSP > 1 && hi == 0) {
        float2v ml; ml[0] = m_run; ml[1] = lt;
        *(float2v*)(Ml + (row * KSP + ks) * 2) = ml;
    }
}

// ---------------- split combine ----------------
__global__ __launch_bounds__(256) void combine(
    const short* __restrict__ Opart, const float* __restrict__ Ml,
    short* __restrict__ Val)
{
    const int row = blockIdx.x;
    const int d = threadIdx.x;
    float m[KSPLIT], l[KSPLIT];
    float M = -1e30f;
#pragma unroll
    for (int i = 0; i < KSPLIT; ++i) {
        float2v v = *(const float2v*)(Ml + ((size_t)row * KSPLIT + i) * 2);
        m[i] = v[0]; l[i] = v[1];
        M = fmaxf(M, m[i]);
    }
    float wsum = 0.f, acc = 0.f;
#pragma unroll
    for (int i = 0; i < KSPLIT; ++i) {
        float wgt = l[i] * exp2f((m[i] - M) * LOG2E);
        wsum += wgt;
        acc += wgt * bf2f(Opart[(size_t)i * (BB * SS * DD) + (size_t)row * DD + d]);
    }
    Val[(size_t)row * DD + d] = f2bf(acc / wsum);
}

// ---------------- out projection -> fp32 ----------------
__global__ __launch_bounds__(256) void oproj_gemm(
    const short* __restrict__ vb, const short* __restrict__ wb,
    const float* __restrict__ bias, float* __restrict__ out)
{
    const int lane = threadIdx.x & 63;
    const int w    = threadIdx.x >> 6;
    const int ln = lane & 15, lg = lane >> 4;
    const int mbase = blockIdx.x * 64 + w * 16;
    const int nbase = blockIdx.y * 64;

    f32x4 acc[4] = {};
    const short* arow = vb + (size_t)(mbase + ln) * DD + 8 * lg;
#pragma unroll
    for (int kk = 0; kk < 8; ++kk) {
        short8 af = *(const short8*)(arow + 32 * kk);
#pragma unroll
        for (int nt = 0; nt < 4; ++nt) {
            short8 bf = *(const short8*)(wb + (size_t)(nbase + 16 * nt + ln) * DD + 32 * kk + 8 * lg);
            acc[nt] = __builtin_amdgcn_mfma_f32_16x16x32_bf16(af, bf, acc[nt], 0, 0, 0);
        }
    }
#pragma unroll
    for (int nt = 0; nt < 4; ++nt) {
        const int e = nbase + 16 * nt + ln;
        const float bv = bias[e];
#pragma unroll
        for (int r = 0; r < 4; ++r)
            out[(size_t)(mbase + 4 * lg + r) * DD + e] = acc[nt][r] + bv;
    }
}

extern "C" void kernel_launch(void* const* d_in, const int* in_sizes, int n_in,
                              void* d_out, int out_size, void* d_ws, size_t ws_size,
                              hipStream_t stream) {
    const float* x    = (const float*)d_in[0];
    const float* Wqkv = (const float*)d_in[1];
    const float* bqkv = (const float*)d_in[2];
    const float* Wo   = (const float*)d_in[3];
    const float* bo   = (const float*)d_in[4];
    float* out = (float*)d_out;
    short* ws  = (short*)d_ws;

    short* w1b = ws + OFF_W1;
    short* w2b = ws + OFF_W2;
    short* Qw  = ws + OFF_Q;
    short* Kw  = ws + OFF_K;
    short* Vt  = ws + OFF_VT;
    short* xb  = ws + OFF_XB;
    short* Val = ws + OFF_VAL;
    short* Opart = ws + OFF_OP;
    float* Ml  = (float*)(ws + OFF_ML);

    cvt_all<<<4352, 256, 0, stream>>>(x, Wqkv, Wo, xb, w1b, w2b);
    qkv_gemm<<<dim3(256, 12), 256, 0, stream>>>(xb, w1b, bqkv, Qw, Kw, Vt);

    constexpr size_t SMEM = 131072;
    if (ws_size >= WS_NEED_SPLIT) {
        (void)hipFuncSetAttribute((const void*)attn<KSPLIT>,
                                  hipFuncAttributeMaxDynamicSharedMemorySize, SMEM);
        attn<KSPLIT><<<16 * KSPLIT * BB, 512, SMEM, stream>>>(Qw, Kw, Vt, Opart, Ml, nullptr);
        combine<<<BB * SS, 256, 0, stream>>>(Opart, Ml, Val);
    } else {
        (void)hipFuncSetAttribute((const void*)attn<1>,
                                  hipFuncAttributeMaxDynamicSharedMemorySize, SMEM);
        attn<1><<<16 * BB, 512, SMEM, stream>>>(Qw, Kw, Vt, nullptr, nullptr, Val);
    }
    oproj_gemm<<<dim3(256, 4), 256, 0, stream>>>(Val, w2b, bo, out);
}

// Round 4
// 188.894 us; speedup vs baseline: 4.9381x; 1.1947x over previous
//
#include <hip/hip_runtime.h>

// MultiHeadAttention: B=4, S=4096, D=256 (single head, fp32 in/out)
// cvt -> QKV GEMM (V stored key-bitswapped) -> 8-wave 32x32 flash attention
// (fragment-order LDS, conflict-free ds_read_b128, split-K) -> combine -> out-proj

#define LOG2E 1.44269504088896340736f

typedef __attribute__((ext_vector_type(8)))  short short8;
typedef __attribute__((ext_vector_type(4)))  short short4v;
typedef __attribute__((ext_vector_type(4)))  float f32x4;
typedef __attribute__((ext_vector_type(16))) float f32x16;
typedef __attribute__((ext_vector_type(4)))  float float4v;
typedef __attribute__((ext_vector_type(2)))  float float2v;

static constexpr int BB = 4, SS = 4096, DD = 256;
static constexpr int KSPLIT = 4;

// ws element offsets (shorts)
static constexpr size_t OFF_W1  = 0;
static constexpr size_t OFF_W2  = 196608;
static constexpr size_t OFF_Q   = 262144;
static constexpr size_t OFF_K   = 4456448;
static constexpr size_t OFF_VT  = 8650752;                // [B][D][Sperm]
static constexpr size_t OFF_XB  = 12845056;               // x bf16; reused as VAL
static constexpr size_t OFF_VAL = 12845056;
static constexpr size_t OFF_OP  = 17039360;               // partial O bf16
static constexpr size_t OFF_ML  = 17039360 + (size_t)KSPLIT * BB * SS * DD;
static constexpr size_t WS_NEED_SPLIT = (OFF_ML + (size_t)BB * SS * KSPLIT * 2) * 2;

__device__ __forceinline__ short f2bf(float f) {
    union { float f; unsigned u; } v; v.f = f;
    unsigned u = v.u;
    u += 0x7fffu + ((u >> 16) & 1u);
    return (short)(u >> 16);
}
__device__ __forceinline__ float bf2f(short s) {
    union { unsigned u; float f; } v; v.u = ((unsigned)(unsigned short)s) << 16;
    return v.f;
}
__device__ __forceinline__ void gload_lds16(const void* g, void* l) {
    __builtin_amdgcn_global_load_lds(
        (const __attribute__((address_space(1))) unsigned int*)g,
        (__attribute__((address_space(3))) unsigned int*)l, 16, 0, 0);
}

// ---------------- fp32 -> bf16 convert ----------------
__global__ __launch_bounds__(256) void cvt_all(
    const float* __restrict__ x, const float* __restrict__ w1,
    const float* __restrict__ w2, short* __restrict__ xb,
    short* __restrict__ w1b, short* __restrict__ w2b)
{
    const int n_x = (BB * SS * DD) / 4;
    const int n_1 = (3 * DD * DD) / 4;
    const int n_2 = (DD * DD) / 4;
    int i = blockIdx.x * 256 + threadIdx.x;
    if (i >= n_x + n_1 + n_2) return;
    const float* src; short* dst; int off;
    if (i < n_x)            { src = x;  dst = xb;  off = i; }
    else if (i < n_x + n_1) { src = w1; dst = w1b; off = i - n_x; }
    else                    { src = w2; dst = w2b; off = i - n_x - n_1; }
    float4v v = *(const float4v*)(src + 4 * (size_t)off);
    short4v o;
    o[0] = f2bf(v[0]); o[1] = f2bf(v[1]); o[2] = f2bf(v[2]); o[3] = f2bf(v[3]);
    *(short4v*)(dst + 4 * (size_t)off) = o;
}

// ---------------- QKV projection ----------------
// Q scaled 1/16, [b][s][d]; K [b][s][d]; V^T [b][d][sPerm] with key bits 2<->3
// swapped so attn's V fragments are 16B-contiguous per lane.
__global__ __launch_bounds__(256) void qkv_gemm(
    const short* __restrict__ xb, const short* __restrict__ wb,
    const float* __restrict__ bias,
    short* __restrict__ Qw, short* __restrict__ Kw, short* __restrict__ Vt)
{
    const int lane = threadIdx.x & 63;
    const int w    = threadIdx.x >> 6;
    const int ln = lane & 15, lg = lane >> 4;
    const int mbase = blockIdx.x * 64 + w * 16;
    const int nbase = blockIdx.y * 64;

    f32x4 acc[4] = {};
    const short* arow = xb + (size_t)(mbase + ln) * DD + 8 * lg;
#pragma unroll
    for (int kk = 0; kk < 8; ++kk) {
        short8 af = *(const short8*)(arow + 32 * kk);
#pragma unroll
        for (int nt = 0; nt < 4; ++nt) {
            short8 bf = *(const short8*)(wb + (size_t)(nbase + 16 * nt + ln) * DD + 32 * kk + 8 * lg);
            acc[nt] = __builtin_amdgcn_mfma_f32_16x16x32_bf16(af, bf, acc[nt], 0, 0, 0);
        }
    }
#pragma unroll
    for (int nt = 0; nt < 4; ++nt) {
        const int e = nbase + 16 * nt + ln;
        const float bv = bias[e];
        const int srow0 = mbase + 4 * lg;
        const int b   = srow0 >> 12;
        const int si0 = srow0 & 4095;
        if (e < 256) {
#pragma unroll
            for (int r = 0; r < 4; ++r) {
                float v = (acc[nt][r] + bv) * 0.0625f;
                Qw[((size_t)b * SS + si0 + r) * DD + e] = f2bf(v);
            }
        } else if (e < 512) {
#pragma unroll
            for (int r = 0; r < 4; ++r)
                Kw[((size_t)b * SS + si0 + r) * DD + (e - 256)] = f2bf(acc[nt][r] + bv);
        } else {
            short4v st;
#pragma unroll
            for (int r = 0; r < 4; ++r) st[r] = f2bf(acc[nt][r] + bv);
            const int sp = (si0 & ~12) | ((si0 & 4) << 1) | ((si0 & 8) >> 1);
            *(short4v*)(Vt + ((size_t)b * DD + (e - 512)) * SS + sp) = st;
        }
    }
}

// ---------------- 8-wave 32x32 split-K flash attention ----------------
// LDS layout = MFMA fragment order: 1KB per fragment block, lane l owns
// bytes [f*1024 + l*16, +16). K blocks f = kt*16+c (kt: 32-key tile, c:
// 16-value d-slice). V blocks f = s*8+dt (s: 16-key group, dt: 32-d tile).
// All ds_read_b128 are contiguous 1024B wave accesses -> conflict-free.
// Staging gathers per-lane global addresses (linear LDS dest).
template<int KSP>
__global__ __launch_bounds__(512, 2) void attn(
    const short* __restrict__ Qw, const short* __restrict__ Kw,
    const short* __restrict__ Vt, short* __restrict__ Opart,
    float* __restrict__ Ml, short* __restrict__ Val)
{
    constexpr int KCHUNK = SS / KSP;
    constexpr int NKB = KCHUNK / 64;
    extern __shared__ __align__(128) char smem[];   // [K0|K1|V0|V1] 32KB each

    const int id = blockIdx.x;
    const int combo = id % (KSP * BB);
    const int qb    = id / (KSP * BB);
    const int ks = combo % KSP;
    const int b  = combo / KSP;
    const int t = threadIdx.x;
    const int lane = t & 63, w = t >> 6;
    const int lr = lane & 31, hi = lane >> 5;
    const int q0 = qb * 256 + w * 32;
    const int kbeg = ks * KCHUNK;

    // Q fragments: B-operand, lane holds Q[q0+lr][16c+8hi .. +7]
    const short* Qp = Qw + ((size_t)b * SS + q0 + lr) * DD + 8 * hi;
    short8 qf[16];
#pragma unroll
    for (int c = 0; c < 16; ++c) qf[c] = *(const short8*)(Qp + 16 * c);

    f32x16 o_acc[8] = {};
    float m_run = -1e30f, l_part = 0.f;

    const char* Kg0 = (const char*)(Kw + ((size_t)b * SS + kbeg) * DD);
    const char* Vg0 = (const char*)(Vt + (size_t)b * DD * SS) + 2 * kbeg;

    // per-lane gather offsets (constant across kb)
    const size_t koff = (size_t)lr * 512 + hi * 16;       // + kt*16384 + c*32
    const size_t voff = (size_t)lr * 8192 + hi * 16;      // + dt*262144 + s*32

    auto stage = [&](int buf, int kb) {
        char* kd = smem + buf * 32768;
        char* vd = smem + 65536 + buf * 32768;
        const char* kg = Kg0 + (size_t)kb * 32768;
        const char* vg = Vg0 + (size_t)kb * 128;
#pragma unroll
        for (int i = 0; i < 4; ++i) {
            const int f = w * 4 + i;                       // 0..31
            const int kt = f >> 4, c = f & 15;
            gload_lds16(kg + (size_t)kt * 16384 + koff + c * 32, kd + f * 1024);
        }
#pragma unroll
        for (int i = 0; i < 4; ++i) {
            const int f = w * 4 + i;                       // 0..31
            const int s = f >> 3, dt = f & 7;
            gload_lds16(vg + (size_t)dt * 262144 + voff + s * 32, vd + f * 1024);
        }
    };

    stage(0, 0);
    __syncthreads();
    int cur = 0;

    for (int kb = 0; kb < NKB; ++kb) {
        if (kb + 1 < NKB) stage(cur ^ 1, kb + 1);

        const char* myK = smem + cur * 32768 + lane * 16;
        const char* myV = smem + 65536 + cur * 32768 + lane * 16;

        // QK^T: S^T[key][q]
        f32x16 sacc[2] = {};
        __builtin_amdgcn_s_setprio(1);
#pragma unroll
        for (int c = 0; c < 16; ++c) {
#pragma unroll
            for (int kt = 0; kt < 2; ++kt) {
                short8 kf = *(const short8*)(myK + (kt * 16 + c) * 1024);
                sacc[kt] = __builtin_amdgcn_mfma_f32_32x32x16_bf16(kf, qf[c], sacc[kt], 0, 0, 0);
            }
        }
        __builtin_amdgcn_s_setprio(0);

        // online softmax (q col in lanes l, l+32)
        float pm = -1e30f;
#pragma unroll
        for (int kt = 0; kt < 2; ++kt)
#pragma unroll
            for (int r = 0; r < 16; ++r) pm = fmaxf(pm, sacc[kt][r]);
        pm = fmaxf(pm, __shfl_xor(pm, 32));
        const float mnew = fmaxf(m_run, pm);
        const float corr = exp2f((m_run - mnew) * LOG2E);
        m_run = mnew;
        float psum = 0.f;
#pragma unroll
        for (int kt = 0; kt < 2; ++kt)
#pragma unroll
            for (int r = 0; r < 16; ++r) {
                float p = exp2f((sacc[kt][r] - mnew) * LOG2E);
                psum += p;
                sacc[kt][r] = p;
            }
        l_part = l_part * corr + psum;
#pragma unroll
        for (int dt = 0; dt < 8; ++dt)
#pragma unroll
            for (int r = 0; r < 16; ++r) o_acc[dt][r] *= corr;

        // PV: O^T[d][q] += V^T[d][key] * P^T[key][q] (keys in stored order)
#pragma unroll
        for (int s = 0; s < 4; ++s) {
            short8 pb;
#pragma unroll
            for (int j = 0; j < 8; ++j)
                pb[j] = f2bf(sacc[s >> 1][(j & 3) + 4 * (j >> 2) + 8 * (s & 1)]);
            __builtin_amdgcn_s_setprio(1);
#pragma unroll
            for (int dt = 0; dt < 8; ++dt) {
                short8 vf = *(const short8*)(myV + (s * 8 + dt) * 1024);
                o_acc[dt] = __builtin_amdgcn_mfma_f32_32x32x16_bf16(vf, pb, o_acc[dt], 0, 0, 0);
            }
            __builtin_amdgcn_s_setprio(0);
        }
        __syncthreads();     // staged tile landed; everyone done reading cur
        cur ^= 1;
    }

    float lt = l_part + __shfl_xor(l_part, 32);
    const float inv = 1.0f / lt;
    const size_t row = (size_t)b * SS + q0 + lr;
    short* vo = (KSP == 1 ? Val : Opart + (size_t)ks * (BB * SS) * DD)
                + row * DD;
#pragma unroll
    for (int dt = 0; dt < 8; ++dt)
#pragma unroll
        for (int g = 0; g < 4; ++g) {
            short4v st;
#pragma unroll
            for (int i = 0; i < 4; ++i) st[i] = f2bf(o_acc[dt][4 * g + i] * inv);
            *(short4v*)(vo + dt * 32 + 8 * g + 4 * hi) = st;
        }
    if (KSP > 1 && hi == 0) {
        float2v ml; ml[0] = m_run; ml[1] = lt;
        *(float2v*)(Ml + (row * KSP + ks) * 2) = ml;
    }
}

// ---------------- split combine ----------------
__global__ __launch_bounds__(256) void combine(
    const short* __restrict__ Opart, const float* __restrict__ Ml,
    short* __restrict__ Val)
{
    const int row = blockIdx.x;
    const int d = threadIdx.x;
    float m[KSPLIT], l[KSPLIT];
    float M = -1e30f;
#pragma unroll
    for (int i = 0; i < KSPLIT; ++i) {
        float2v v = *(const float2v*)(Ml + ((size_t)row * KSPLIT + i) * 2);
        m[i] = v[0]; l[i] = v[1];
        M = fmaxf(M, m[i]);
    }
    float wsum = 0.f, acc = 0.f;
#pragma unroll
    for (int i = 0; i < KSPLIT; ++i) {
        float wgt = l[i] * exp2f((m[i] - M) * LOG2E);
        wsum += wgt;
        acc += wgt * bf2f(Opart[(size_t)i * (BB * SS * DD) + (size_t)row * DD + d]);
    }
    Val[(size_t)row * DD + d] = f2bf(acc / wsum);
}

// ---------------- out projection -> fp32 ----------------
__global__ __launch_bounds__(256) void oproj_gemm(
    const short* __restrict__ vb, const short* __restrict__ wb,
    const float* __restrict__ bias, float* __restrict__ out)
{
    const int lane = threadIdx.x & 63;
    const int w    = threadIdx.x >> 6;
    const int ln = lane & 15, lg = lane >> 4;
    const int mbase = blockIdx.x * 64 + w * 16;
    const int nbase = blockIdx.y * 64;

    f32x4 acc[4] = {};
    const short* arow = vb + (size_t)(mbase + ln) * DD + 8 * lg;
#pragma unroll
    for (int kk = 0; kk < 8; ++kk) {
        short8 af = *(const short8*)(arow + 32 * kk);
#pragma unroll
        for (int nt = 0; nt < 4; ++nt) {
            short8 bf = *(const short8*)(wb + (size_t)(nbase + 16 * nt + ln) * DD + 32 * kk + 8 * lg);
            acc[nt] = __builtin_amdgcn_mfma_f32_16x16x32_bf16(af, bf, acc[nt], 0, 0, 0);
        }
    }
#pragma unroll
    for (int nt = 0; nt < 4; ++nt) {
        const int e = nbase + 16 * nt + ln;
        const float bv = bias[e];
#pragma unroll
        for (int r = 0; r < 4; ++r)
            out[(size_t)(mbase + 4 * lg + r) * DD + e] = acc[nt][r] + bv;
    }
}

extern "C" void kernel_launch(void* const* d_in, const int* in_sizes, int n_in,
                              void* d_out, int out_size, void* d_ws, size_t ws_size,
                              hipStream_t stream) {
    const float* x    = (const float*)d_in[0];
    const float* Wqkv = (const float*)d_in[1];
    const float* bqkv = (const float*)d_in[2];
    const float* Wo   = (const float*)d_in[3];
    const float* bo   = (const float*)d_in[4];
    float* out = (float*)d_out;
    short* ws  = (short*)d_ws;

    short* w1b = ws + OFF_W1;
    short* w2b = ws + OFF_W2;
    short* Qw  = ws + OFF_Q;
    short* Kw  = ws + OFF_K;
    short* Vt  = ws + OFF_VT;
    short* xb  = ws + OFF_XB;
    short* Val = ws + OFF_VAL;
    short* Opart = ws + OFF_OP;
    float* Ml  = (float*)(ws + OFF_ML);

    cvt_all<<<4352, 256, 0, stream>>>(x, Wqkv, Wo, xb, w1b, w2b);
    qkv_gemm<<<dim3(256, 12), 256, 0, stream>>>(xb, w1b, bqkv, Qw, Kw, Vt);

    constexpr size_t SMEM = 131072;
    if (ws_size >= WS_NEED_SPLIT) {
        (void)hipFuncSetAttribute((const void*)attn<KSPLIT>,
                                  hipFuncAttributeMaxDynamicSharedMemorySize, SMEM);
        attn<KSPLIT><<<16 * KSPLIT * BB, 512, SMEM, stream>>>(Qw, Kw, Vt, Opart, Ml, nullptr);
        combine<<<BB * SS, 256, 0, stream>>>(Opart, Ml, Val);
    } else {
        (void)hipFuncSetAttribute((const void*)attn<1>,
                                  hipFuncAttributeMaxDynamicSharedMemorySize, SMEM);
        attn<1><<<16 * BB, 512, SMEM, stream>>>(Qw, Kw, Vt, nullptr, nullptr, Val);
    }
    oproj_gemm<<<dim3(256, 4), 256, 0, stream>>>(Val, w2b, bo, out);
}